// Round 1
// baseline (1342.266 us; speedup 1.0000x reference)
//
#include <hip/hip_runtime.h>
#include <cstdint>
#include <cstddef>

typedef int v4i __attribute__((ext_vector_type(4)));
typedef int v16i __attribute__((ext_vector_type(16)));

#define BM 128
#define BN 128
#define BK 64

// ---------------- async global->LDS, 16B per lane ----------------
__device__ __forceinline__ void gld_lds16(const void* g, void* l) {
  __builtin_amdgcn_global_load_lds(
      (const __attribute__((address_space(1))) unsigned int*)g,
      (__attribute__((address_space(3))) unsigned int*)l, 16, 0, 0);
}

// Stage a 128-row x 64-byte tile into LDS with XOR chunk swizzle.
// LDS chunk (r, cs) holds global chunk (r, cs ^ ((r>>1)&3)).
// Wave-uniform LDS base + lane*16 contract respected: dst = lds + (f&~63)*16.
__device__ __forceinline__ void stage_tile(const int8_t* __restrict__ g0, int K,
                                           int kt, int8_t* lds, int tid) {
#pragma unroll
  for (int issue = 0; issue < 2; ++issue) {
    int f = issue * 256 + tid;
    int r = f >> 2;
    int cg = (f & 3) ^ ((r >> 1) & 3);
    gld_lds16(g0 + (size_t)r * K + kt + cg * 16, lds + (f & ~63) * 16);
  }
}

// Read one 32x32x32 i8 MFMA operand fragment (16 bytes) from a swizzled tile.
// Operand layout: row = lane&31, k-bytes = (lane>>5)*16 + j within k-step kk.
__device__ __forceinline__ v4i read_frag(const int8_t* lds, int row0, int kk, int lane) {
  int r = row0 + (lane & 31);
  int cs = (kk * 2 + (lane >> 5)) ^ ((r >> 1) & 3);
  return *(const v4i*)(lds + r * 64 + cs * 16);
}

// ---------------- per-row symmetric int8 quantization ----------------
// s = max(max|row|/127, 1e-8); q = clamp(rint(x/s), -128, 127)  (matches jnp exactly)
__global__ __launch_bounds__(256) void quant_rows(const float* __restrict__ X, int C,
                                                  int8_t* __restrict__ Q,
                                                  float* __restrict__ S) {
  const int row = blockIdx.x;
  const float* x = X + (size_t)row * C;
  const int tid = threadIdx.x;
  float mx = 0.f;
  for (int i = tid * 4; i < C; i += 1024) {
    const float4 v = *(const float4*)(x + i);
    mx = fmaxf(mx, fmaxf(fmaxf(fabsf(v.x), fabsf(v.y)), fmaxf(fabsf(v.z), fabsf(v.w))));
  }
#pragma unroll
  for (int off = 32; off; off >>= 1) mx = fmaxf(mx, __shfl_xor(mx, off));
  __shared__ float wmx[4];
  if ((tid & 63) == 0) wmx[tid >> 6] = mx;
  __syncthreads();
  mx = fmaxf(fmaxf(wmx[0], wmx[1]), fmaxf(wmx[2], wmx[3]));
  const float s = fmaxf(mx / 127.0f, 1e-8f);
  if (tid == 0) S[row] = s;
  int8_t* q = Q + (size_t)row * C;
  for (int i = tid * 4; i < C; i += 1024) {
    const float4 v = *(const float4*)(x + i);
    int q0 = (int)fminf(fmaxf(rintf(v.x / s), -128.f), 127.f);
    int q1 = (int)fminf(fmaxf(rintf(v.y / s), -128.f), 127.f);
    int q2 = (int)fminf(fmaxf(rintf(v.z / s), -128.f), 127.f);
    int q3 = (int)fminf(fmaxf(rintf(v.w / s), -128.f), 127.f);
    *(int*)(q + i) = (q0 & 255) | ((q1 & 255) << 8) | ((q2 & 255) << 16) | ((q3 & 255) << 24);
  }
}

// ---------------- fused gate+up int8 GEMM, SwiGLU epilogue -> h fp32 ----------------
__global__ __launch_bounds__(256, 2) void gemm_gateup(
    const int8_t* __restrict__ Xq, const float* __restrict__ sx,
    const int8_t* __restrict__ Wg, const float* __restrict__ sg,
    const int8_t* __restrict__ Wu, const float* __restrict__ su,
    float* __restrict__ H, int M, int N, int K) {
  __shared__ __align__(16) int8_t lsA[BM * BK];
  __shared__ __align__(16) int8_t lsG[BN * BK];
  __shared__ __align__(16) int8_t lsU[BN * BK];
  const int tid = threadIdx.x;
  const int lane = tid & 63;
  const int wave = tid >> 6;
  const int wr = wave >> 1, wc = wave & 1;
  const size_t rowA = (size_t)blockIdx.x * BM;
  const size_t rowB = (size_t)blockIdx.y * BN;
  const int8_t* gA = Xq + rowA * K;
  const int8_t* gG = Wg + rowB * K;
  const int8_t* gU = Wu + rowB * K;

  v16i accg[2][2], accu[2][2];
#pragma unroll
  for (int a = 0; a < 2; ++a)
#pragma unroll
    for (int b = 0; b < 2; ++b)
#pragma unroll
      for (int r = 0; r < 16; ++r) { accg[a][b][r] = 0; accu[a][b][r] = 0; }

  for (int kt = 0; kt < K; kt += BK) {
    __syncthreads();
    stage_tile(gA, K, kt, lsA, tid);
    stage_tile(gG, K, kt, lsG, tid);
    stage_tile(gU, K, kt, lsU, tid);
    __syncthreads();
#pragma unroll
    for (int kk = 0; kk < 2; ++kk) {
      v4i a0 = read_frag(lsA, wr * 64, kk, lane);
      v4i a1 = read_frag(lsA, wr * 64 + 32, kk, lane);
#pragma unroll
      for (int ni = 0; ni < 2; ++ni) {
        v4i bg = read_frag(lsG, wc * 64 + ni * 32, kk, lane);
        v4i bu = read_frag(lsU, wc * 64 + ni * 32, kk, lane);
        accg[0][ni] = __builtin_amdgcn_mfma_i32_32x32x32_i8(a0, bg, accg[0][ni], 0, 0, 0);
        accg[1][ni] = __builtin_amdgcn_mfma_i32_32x32x32_i8(a1, bg, accg[1][ni], 0, 0, 0);
        accu[0][ni] = __builtin_amdgcn_mfma_i32_32x32x32_i8(a0, bu, accu[0][ni], 0, 0, 0);
        accu[1][ni] = __builtin_amdgcn_mfma_i32_32x32x32_i8(a1, bu, accu[1][ni], 0, 0, 0);
      }
    }
  }

#pragma unroll
  for (int mi = 0; mi < 2; ++mi)
#pragma unroll
    for (int ni = 0; ni < 2; ++ni) {
#pragma unroll
      for (int r = 0; r < 16; ++r) {
        int rl = wr * 64 + mi * 32 + (r & 3) + 8 * (r >> 2) + 4 * (lane >> 5);
        int cl = wc * 64 + ni * 32 + (lane & 31);
        size_t m = rowA + rl, n = rowB + cl;
        float sxm = sx[m];
        float g = (float)accg[mi][ni][r] * sxm * sg[n];
        float u = (float)accu[mi][ni][r] * sxm * su[n];
        float hv = g / (1.0f + __expf(-g)) * u;  // silu(g)*u
        H[m * (size_t)N + n] = hv;
      }
    }
}

// ---------------- int8 GEMM, scale epilogue -> fp32 out ----------------
__global__ __launch_bounds__(256, 2) void gemm_down(
    const int8_t* __restrict__ Aq, const float* __restrict__ sa,
    const int8_t* __restrict__ Bq, const float* __restrict__ sb,
    float* __restrict__ C, int M, int N, int K) {
  __shared__ __align__(16) int8_t lsA[BM * BK];
  __shared__ __align__(16) int8_t lsB[BN * BK];
  const int tid = threadIdx.x;
  const int lane = tid & 63;
  const int wave = tid >> 6;
  const int wr = wave >> 1, wc = wave & 1;
  const size_t rowA = (size_t)blockIdx.x * BM;
  const size_t rowB = (size_t)blockIdx.y * BN;
  const int8_t* gA = Aq + rowA * K;
  const int8_t* gB = Bq + rowB * K;

  v16i acc[2][2];
#pragma unroll
  for (int a = 0; a < 2; ++a)
#pragma unroll
    for (int b = 0; b < 2; ++b)
#pragma unroll
      for (int r = 0; r < 16; ++r) acc[a][b][r] = 0;

  for (int kt = 0; kt < K; kt += BK) {
    __syncthreads();
    stage_tile(gA, K, kt, lsA, tid);
    stage_tile(gB, K, kt, lsB, tid);
    __syncthreads();
#pragma unroll
    for (int kk = 0; kk < 2; ++kk) {
      v4i a0 = read_frag(lsA, wr * 64, kk, lane);
      v4i a1 = read_frag(lsA, wr * 64 + 32, kk, lane);
      v4i b0 = read_frag(lsB, wc * 64, kk, lane);
      v4i b1 = read_frag(lsB, wc * 64 + 32, kk, lane);
      acc[0][0] = __builtin_amdgcn_mfma_i32_32x32x32_i8(a0, b0, acc[0][0], 0, 0, 0);
      acc[0][1] = __builtin_amdgcn_mfma_i32_32x32x32_i8(a0, b1, acc[0][1], 0, 0, 0);
      acc[1][0] = __builtin_amdgcn_mfma_i32_32x32x32_i8(a1, b0, acc[1][0], 0, 0, 0);
      acc[1][1] = __builtin_amdgcn_mfma_i32_32x32x32_i8(a1, b1, acc[1][1], 0, 0, 0);
    }
  }

#pragma unroll
  for (int mi = 0; mi < 2; ++mi)
#pragma unroll
    for (int ni = 0; ni < 2; ++ni) {
#pragma unroll
      for (int r = 0; r < 16; ++r) {
        int rl = wr * 64 + mi * 32 + (r & 3) + 8 * (r >> 2) + 4 * (lane >> 5);
        int cl = wc * 64 + ni * 32 + (lane & 31);
        size_t m = rowA + rl, n = rowB + cl;
        C[m * (size_t)N + n] = (float)acc[mi][ni][r] * sa[m] * sb[n];
      }
    }
}

extern "C" void kernel_launch(void* const* d_in, const int* in_sizes, int n_in,
                              void* d_out, int out_size, void* d_ws, size_t ws_size,
                              hipStream_t stream) {
  const int T = 4096, HID = 4096, INTER = 11008;
  const float* x  = (const float*)d_in[0];
  const float* wg = (const float*)d_in[1];
  const float* wu = (const float*)d_in[2];
  const float* wd = (const float*)d_in[3];
  float* out = (float*)d_out;

  char* base = (char*)d_ws;
  size_t off = 0;
  auto alloc = [&](size_t b) {
    void* p = base + off;
    off += (b + 255) & ~(size_t)255;
    return p;
  };
  int8_t* xq  = (int8_t*)alloc((size_t)T * HID);
  float*  sx  = (float*)alloc((size_t)T * 4);
  int8_t* wgq = (int8_t*)alloc((size_t)INTER * HID);
  float*  sg  = (float*)alloc((size_t)INTER * 4);
  int8_t* wuq = (int8_t*)alloc((size_t)INTER * HID);
  float*  su  = (float*)alloc((size_t)INTER * 4);
  int8_t* wdq = (int8_t*)alloc((size_t)HID * INTER);
  float*  sd  = (float*)alloc((size_t)HID * 4);
  const size_t fixed = off;

  // choose largest token-chunk whose h/hq buffers fit in ws
  auto need = [&](int ch) {
    size_t n = fixed;
    n += (((size_t)ch * INTER) + 255) & ~(size_t)255;      // hq
    n += (((size_t)ch * 4) + 255) & ~(size_t)255;          // sh
    n += (((size_t)ch * INTER * 4) + 255) & ~(size_t)255;  // h
    return n;
  };
  int CH = 4096;
  while (CH > 128 && need(CH) > ws_size) CH >>= 1;
  int8_t* hq = (int8_t*)alloc((size_t)CH * INTER);
  float*  sh = (float*)alloc((size_t)CH * 4);
  float*  h  = (float*)alloc((size_t)CH * INTER * 4);

  // quantize activations and weights (exact int8 per-row, matches jnp bitwise)
  quant_rows<<<T, 256, 0, stream>>>(x, HID, xq, sx);
  quant_rows<<<INTER, 256, 0, stream>>>(wg, HID, wgq, sg);
  quant_rows<<<INTER, 256, 0, stream>>>(wu, HID, wuq, su);
  quant_rows<<<HID, 256, 0, stream>>>(wd, INTER, wdq, sd);

  for (int c = 0; c < T; c += CH) {
    dim3 g1(CH / BM, INTER / BN);
    gemm_gateup<<<g1, 256, 0, stream>>>(xq + (size_t)c * HID, sx + c,
                                        wgq, sg, wuq, su, h, CH, INTER, HID);
    quant_rows<<<CH, 256, 0, stream>>>(h, INTER, hq, sh);
    dim3 g2(CH / BM, HID / BN);
    gemm_down<<<g2, 256, 0, stream>>>(hq, sh, wdq, sd, out + (size_t)c * HID,
                                      CH, HID, INTER);
  }
}

// Round 2
// 1222.621 us; speedup vs baseline: 1.0979x; 1.0979x over previous
//
#include <hip/hip_runtime.h>
#include <cstdint>
#include <cstddef>

typedef int v4i __attribute__((ext_vector_type(4)));
typedef int v16i __attribute__((ext_vector_type(16)));

#define BM 128
#define BN 128
#define BK 128  // bytes of K per tile (i8)

// ---------------- async global->LDS, 16B per lane ----------------
__device__ __forceinline__ void gld_lds16(const void* g, void* l) {
  __builtin_amdgcn_global_load_lds(
      (const __attribute__((address_space(1))) unsigned int*)g,
      (__attribute__((address_space(3))) unsigned int*)l, 16, 0, 0);
}

// Stage a 128-row x 128-byte tile into LDS with XOR chunk swizzle.
// LDS chunk (r, cs) holds global chunk cg = cs ^ (r&7).
// Row stride 128 B spans all 32 banks; swizzle makes 8 consecutive lanes'
// b128 reads (8 consecutive rows, same logical chunk) hit 8 distinct
// bank-quads. global_load_lds contract: wave-uniform base + lane*16.
__device__ __forceinline__ void stage_tile(const int8_t* __restrict__ g0, int K,
                                           int kt, int8_t* lds, int tid) {
#pragma unroll
  for (int issue = 0; issue < 4; ++issue) {
    int f = issue * 256 + tid;
    int r = f >> 3;
    int cg = (f & 7) ^ (r & 7);
    gld_lds16(g0 + (size_t)r * K + kt + cg * 16, lds + (f & ~63) * 16);
  }
}

// Read one 32x32x32 i8 MFMA operand fragment (16 bytes) from a swizzled tile.
// Operand layout (verified R1): row = lane&31, k-chunk = kk*2 + (lane>>5).
__device__ __forceinline__ v4i read_frag(const int8_t* lds, int row0, int kk, int lane) {
  int r = row0 + (lane & 31);
  int cs = (kk * 2 + (lane >> 5)) ^ (r & 7);
  return *(const v4i*)(lds + r * BK + cs * 16);
}

// ---------------- per-row symmetric int8 quantization (single HBM pass) ----
// s = max(max|row|/127, 1e-8); q = clamp(rint(x/s), -128, 127)  (matches jnp
// bitwise: true division, rint = round-half-even). Row slice cached in regs.
template <int MAXIT>
__global__ __launch_bounds__(256) void quant_rows(const float* __restrict__ X, int C,
                                                  int8_t* __restrict__ Q,
                                                  float* __restrict__ S) {
  const int row = blockIdx.x;
  const float* x = X + (size_t)row * C;
  const int tid = threadIdx.x;
  float4 buf[MAXIT];
  float mx = 0.f;
#pragma unroll
  for (int it = 0; it < MAXIT; ++it) {
    int i = tid * 4 + it * 1024;
    if (i < C) {
      const float4 v = *(const float4*)(x + i);
      buf[it] = v;
      mx = fmaxf(mx, fmaxf(fmaxf(fabsf(v.x), fabsf(v.y)), fmaxf(fabsf(v.z), fabsf(v.w))));
    }
  }
#pragma unroll
  for (int off = 32; off; off >>= 1) mx = fmaxf(mx, __shfl_xor(mx, off));
  __shared__ float wmx[4];
  if ((tid & 63) == 0) wmx[tid >> 6] = mx;
  __syncthreads();
  mx = fmaxf(fmaxf(wmx[0], wmx[1]), fmaxf(wmx[2], wmx[3]));
  const float s = fmaxf(mx / 127.0f, 1e-8f);
  if (tid == 0) S[row] = s;
  int8_t* q = Q + (size_t)row * C;
#pragma unroll
  for (int it = 0; it < MAXIT; ++it) {
    int i = tid * 4 + it * 1024;
    if (i < C) {
      const float4 v = buf[it];
      int q0 = (int)fminf(fmaxf(rintf(v.x / s), -128.f), 127.f);
      int q1 = (int)fminf(fmaxf(rintf(v.y / s), -128.f), 127.f);
      int q2 = (int)fminf(fmaxf(rintf(v.z / s), -128.f), 127.f);
      int q3 = (int)fminf(fmaxf(rintf(v.w / s), -128.f), 127.f);
      *(int*)(q + i) = (q0 & 255) | ((q1 & 255) << 8) | ((q2 & 255) << 16) | ((q3 & 255) << 24);
    }
  }
}

// ---------------- fused gate+up int8 GEMM, SwiGLU epilogue -> h fp32 ----------------
__global__ __launch_bounds__(256, 2) void gemm_gateup(
    const int8_t* __restrict__ Xq, const float* __restrict__ sx,
    const int8_t* __restrict__ Wg, const float* __restrict__ sg,
    const int8_t* __restrict__ Wu, const float* __restrict__ su,
    float* __restrict__ H, int M, int N, int K) {
  __shared__ __align__(16) int8_t lsA[BM * BK];
  __shared__ __align__(16) int8_t lsG[BN * BK];
  __shared__ __align__(16) int8_t lsU[BN * BK];
  const int tid = threadIdx.x;
  const int lane = tid & 63;
  const int wave = tid >> 6;
  const int wr = wave >> 1, wc = wave & 1;
  const size_t rowA = (size_t)blockIdx.x * BM;
  const size_t rowB = (size_t)blockIdx.y * BN;
  const int8_t* gA = Xq + rowA * K;
  const int8_t* gG = Wg + rowB * K;
  const int8_t* gU = Wu + rowB * K;

  v16i accg[2][2], accu[2][2];
#pragma unroll
  for (int a = 0; a < 2; ++a)
#pragma unroll
    for (int b = 0; b < 2; ++b)
#pragma unroll
      for (int r = 0; r < 16; ++r) { accg[a][b][r] = 0; accu[a][b][r] = 0; }

  for (int kt = 0; kt < K; kt += BK) {
    __syncthreads();
    stage_tile(gA, K, kt, lsA, tid);
    stage_tile(gG, K, kt, lsG, tid);
    stage_tile(gU, K, kt, lsU, tid);
    __syncthreads();
#pragma unroll
    for (int kk = 0; kk < 4; ++kk) {
      v4i a0 = read_frag(lsA, wr * 64, kk, lane);
      v4i a1 = read_frag(lsA, wr * 64 + 32, kk, lane);
#pragma unroll
      for (int ni = 0; ni < 2; ++ni) {
        v4i bg = read_frag(lsG, wc * 64 + ni * 32, kk, lane);
        v4i bu = read_frag(lsU, wc * 64 + ni * 32, kk, lane);
        accg[0][ni] = __builtin_amdgcn_mfma_i32_32x32x32_i8(a0, bg, accg[0][ni], 0, 0, 0);
        accg[1][ni] = __builtin_amdgcn_mfma_i32_32x32x32_i8(a1, bg, accg[1][ni], 0, 0, 0);
        accu[0][ni] = __builtin_amdgcn_mfma_i32_32x32x32_i8(a0, bu, accu[0][ni], 0, 0, 0);
        accu[1][ni] = __builtin_amdgcn_mfma_i32_32x32x32_i8(a1, bu, accu[1][ni], 0, 0, 0);
      }
    }
  }

#pragma unroll
  for (int mi = 0; mi < 2; ++mi)
#pragma unroll
    for (int ni = 0; ni < 2; ++ni) {
#pragma unroll
      for (int r = 0; r < 16; ++r) {
        int rl = wr * 64 + mi * 32 + (r & 3) + 8 * (r >> 2) + 4 * (lane >> 5);
        int cl = wc * 64 + ni * 32 + (lane & 31);
        size_t m = rowA + rl, n = rowB + cl;
        float sxm = sx[m];
        float g = (float)accg[mi][ni][r] * sxm * sg[n];
        float u = (float)accu[mi][ni][r] * sxm * su[n];
        float hv = g / (1.0f + __expf(-g)) * u;  // silu(g)*u
        H[m * (size_t)N + n] = hv;
      }
    }
}

// ---------------- int8 GEMM, scale epilogue -> fp32 out ----------------
__global__ __launch_bounds__(256, 2) void gemm_down(
    const int8_t* __restrict__ Aq, const float* __restrict__ sa,
    const int8_t* __restrict__ Bq, const float* __restrict__ sb,
    float* __restrict__ C, int M, int N, int K) {
  __shared__ __align__(16) int8_t lsA[BM * BK];
  __shared__ __align__(16) int8_t lsB[BN * BK];
  const int tid = threadIdx.x;
  const int lane = tid & 63;
  const int wave = tid >> 6;
  const int wr = wave >> 1, wc = wave & 1;
  const size_t rowA = (size_t)blockIdx.x * BM;
  const size_t rowB = (size_t)blockIdx.y * BN;
  const int8_t* gA = Aq + rowA * K;
  const int8_t* gB = Bq + rowB * K;

  v16i acc[2][2];
#pragma unroll
  for (int a = 0; a < 2; ++a)
#pragma unroll
    for (int b = 0; b < 2; ++b)
#pragma unroll
      for (int r = 0; r < 16; ++r) acc[a][b][r] = 0;

  for (int kt = 0; kt < K; kt += BK) {
    __syncthreads();
    stage_tile(gA, K, kt, lsA, tid);
    stage_tile(gB, K, kt, lsB, tid);
    __syncthreads();
#pragma unroll
    for (int kk = 0; kk < 4; ++kk) {
      v4i a0 = read_frag(lsA, wr * 64, kk, lane);
      v4i a1 = read_frag(lsA, wr * 64 + 32, kk, lane);
      v4i b0 = read_frag(lsB, wc * 64, kk, lane);
      v4i b1 = read_frag(lsB, wc * 64 + 32, kk, lane);
      acc[0][0] = __builtin_amdgcn_mfma_i32_32x32x32_i8(a0, b0, acc[0][0], 0, 0, 0);
      acc[0][1] = __builtin_amdgcn_mfma_i32_32x32x32_i8(a0, b1, acc[0][1], 0, 0, 0);
      acc[1][0] = __builtin_amdgcn_mfma_i32_32x32x32_i8(a1, b0, acc[1][0], 0, 0, 0);
      acc[1][1] = __builtin_amdgcn_mfma_i32_32x32x32_i8(a1, b1, acc[1][1], 0, 0, 0);
    }
  }

#pragma unroll
  for (int mi = 0; mi < 2; ++mi)
#pragma unroll
    for (int ni = 0; ni < 2; ++ni) {
#pragma unroll
      for (int r = 0; r < 16; ++r) {
        int rl = wr * 64 + mi * 32 + (r & 3) + 8 * (r >> 2) + 4 * (lane >> 5);
        int cl = wc * 64 + ni * 32 + (lane & 31);
        size_t m = rowA + rl, n = rowB + cl;
        C[m * (size_t)N + n] = (float)acc[mi][ni][r] * sa[m] * sb[n];
      }
    }
}

extern "C" void kernel_launch(void* const* d_in, const int* in_sizes, int n_in,
                              void* d_out, int out_size, void* d_ws, size_t ws_size,
                              hipStream_t stream) {
  const int T = 4096, HID = 4096, INTER = 11008;
  const float* x  = (const float*)d_in[0];
  const float* wg = (const float*)d_in[1];
  const float* wu = (const float*)d_in[2];
  const float* wd = (const float*)d_in[3];
  float* out = (float*)d_out;

  char* base = (char*)d_ws;
  size_t off = 0;
  auto alloc = [&](size_t b) {
    void* p = base + off;
    off += (b + 255) & ~(size_t)255;
    return p;
  };
  int8_t* xq  = (int8_t*)alloc((size_t)T * HID);
  float*  sx  = (float*)alloc((size_t)T * 4);
  int8_t* wgq = (int8_t*)alloc((size_t)INTER * HID);
  float*  sg  = (float*)alloc((size_t)INTER * 4);
  int8_t* wuq = (int8_t*)alloc((size_t)INTER * HID);
  float*  su  = (float*)alloc((size_t)INTER * 4);
  int8_t* wdq = (int8_t*)alloc((size_t)HID * INTER);
  float*  sd  = (float*)alloc((size_t)HID * 4);
  const size_t fixed = off;

  // choose largest token-chunk whose h/hq buffers fit in ws
  auto need = [&](int ch) {
    size_t n = fixed;
    n += (((size_t)ch * INTER) + 255) & ~(size_t)255;      // hq
    n += (((size_t)ch * 4) + 255) & ~(size_t)255;          // sh
    n += (((size_t)ch * INTER * 4) + 255) & ~(size_t)255;  // h
    return n;
  };
  int CH = 4096;
  while (CH > 128 && need(CH) > ws_size) CH >>= 1;
  int8_t* hq = (int8_t*)alloc((size_t)CH * INTER);
  float*  sh = (float*)alloc((size_t)CH * 4);
  float*  h  = (float*)alloc((size_t)CH * INTER * 4);

  // quantize activations and weights (single HBM pass, exact int8 per-row)
  quant_rows<4><<<T, 256, 0, stream>>>(x, HID, xq, sx);
  quant_rows<4><<<INTER, 256, 0, stream>>>(wg, HID, wgq, sg);
  quant_rows<4><<<INTER, 256, 0, stream>>>(wu, HID, wuq, su);
  quant_rows<11><<<HID, 256, 0, stream>>>(wd, INTER, wdq, sd);

  for (int c = 0; c < T; c += CH) {
    dim3 g1(CH / BM, INTER / BN);
    gemm_gateup<<<g1, 256, 0, stream>>>(xq + (size_t)c * HID, sx + c,
                                        wgq, sg, wuq, su, h, CH, INTER, HID);
    quant_rows<11><<<CH, 256, 0, stream>>>(h, INTER, hq, sh);
    dim3 g2(CH / BM, HID / BN);
    gemm_down<<<g2, 256, 0, stream>>>(hq, sh, wdq, sd, out + (size_t)c * HID,
                                      CH, HID, INTER);
  }
}